// Round 9
// baseline (292.099 us; speedup 1.0000x reference)
//
#include <hip/hip_runtime.h>
#include <hip/hip_bf16.h>

// GraphSAGE 2-layer inference, N=50000, E=600000, D=128.
// R9: fused aggregate+GEMM per layer (6 -> 4 launches, aggb round-trip gone):
//   prep:     zero cursor + f2bf(x) + weight fragment-transpose   (R8-proven)
//   fill_pad: padded CSR build                                    (R8-proven)
//   fused1:   hb  = relu(mean-agg(xb)@Wl1 + b1 + xb@Wr1)
//   fused2:   out =      mean-agg(hb)@Wl2 + b2 + hb@Wr2
// Fused kernel: 64-row tile/block; Phase A: wave gathers its own 16 nodes
// (R8 gather body) into a 16KB LDS tile, XOR-swizzled (pos = chunk^(row&15))
// so both the 16-lane writes and the MFMA A-frag reads are 2-way/free;
// Phase B: R8 MFMA body, agg A-frags from LDS, lin_r A-frags from global.
// LDS = 64KB weights + 16KB tile = 80KB -> 2 blocks/CU.

#define D 128
#define PAD 64

typedef __attribute__((ext_vector_type(8))) short bf16x8;
typedef __attribute__((ext_vector_type(4))) float f32x4;

__device__ __forceinline__ unsigned short f2bf(float f) {
    __hip_bfloat16 b = __float2bfloat16(f);
    return *(unsigned short*)&b;
}
__device__ __forceinline__ float bf_lo(unsigned u) { return __uint_as_float(u << 16); }
__device__ __forceinline__ float bf_hi(unsigned u) { return __uint_as_float(u & 0xffff0000u); }

// ---------------- fused prep: zero cursor + f2bf(x) + wt fragment transpose (R8-proven) ----------------
__global__ __launch_bounds__(256) void prep_kernel(
    const float* __restrict__ x, unsigned short* __restrict__ xb, int n4,
    const float* __restrict__ w0, const float* __restrict__ w1,
    const float* __restrict__ w2, const float* __restrict__ w3,
    unsigned short* __restrict__ o0, unsigned short* __restrict__ o1,
    unsigned short* __restrict__ o2, unsigned short* __restrict__ o3,
    int* __restrict__ cursor, int n, int nb_f2bf) {
    int b = blockIdx.x;
    int tid = threadIdx.x;
    if (b < nb_f2bf) {
        int i = b * 256 + tid;
        if (i < n4) {
            float4 v = ((const float4*)x)[i];
            ushort4 o;
            o.x = f2bf(v.x); o.y = f2bf(v.y); o.z = f2bf(v.z); o.w = f2bf(v.w);
            ((ushort4*)xb)[i] = o;
        }
    } else if (b < nb_f2bf + 256) {
        // weights fp32 [k][n] -> bf16 MFMA-fragment order (R6..R8-proven):
        // frag f = c*4+kt; elem [f*512 + lane*8 + j] = W[kt*32+(lane>>4)*8+j][c*16+(lane&15)]
        int t = (b - nb_f2bf) * 256 + tid;       // 0 .. 65535
        int m = t >> 14;
        int r = t & 16383;
        int f = r >> 9;
        int q = r & 511;
        int lane = q >> 3, j = q & 7;
        int kt = f & 3, c = f >> 2;
        int k  = kt * 32 + (lane >> 4) * 8 + j;
        int nn = c * 16 + (lane & 15);
        const float* w = (m == 0) ? w0 : (m == 1) ? w1 : (m == 2) ? w2 : w3;
        unsigned short* o = (m == 0) ? o0 : (m == 1) ? o1 : (m == 2) ? o2 : o3;
        o[r] = f2bf(w[k * 128 + nn]);
    } else {
        int i = (b - nb_f2bf - 256) * 256 + tid;
        if (i < n) cursor[i] = 0;
    }
}

// ---------------- padded-CSR fill (R8-proven) ----------------
__global__ void fill_pad_kernel(const int* __restrict__ src, const int* __restrict__ dst,
                                int* __restrict__ cursor, int* __restrict__ csr, int E) {
    int i = blockIdx.x * blockDim.x + threadIdx.x;
    if (i < E) {
        int d = dst[i];
        int p = atomicAdd(&cursor[d], 1);
        if (p < PAD) csr[d * PAD + p] = src[i];
    }
}

// ---------------- fused aggregate + MFMA GEMM ----------------
// out = mean-agg(feat)@Wl + feat@Wr + bias (optional relu).
// feat bf16 [n][128] is BOTH the gather table and the lin_r input.
__global__ __launch_bounds__(256) void fused_agg_gemm_kernel(
    const unsigned short* __restrict__ feat,
    const unsigned short* __restrict__ WfL, const unsigned short* __restrict__ WfR,
    const int* __restrict__ deg, const int* __restrict__ csr,
    const float* __restrict__ bias, unsigned short* __restrict__ out_bf,
    float* __restrict__ out_f32, int n, int mode) {
    __shared__ unsigned short ldsw[2][32][512];   // 64 KB fragment-ordered weights
    __shared__ unsigned short ldsa[64][128];      // 16 KB agg tile, XOR-swizzled chunks

    const int tid = threadIdx.x;
    // Stage both weight tables (coalesced 16B chunks; consumed after the sync).
    {
        const uint4* srcL = (const uint4*)WfL;    // 2048 uint4 each
        const uint4* srcR = (const uint4*)WfR;
        uint4* dstw = (uint4*)&ldsw[0][0][0];
#pragma unroll
        for (int it = 0; it < 8; ++it) {
            int i = it * 256 + tid;
            dstw[i]        = srcL[i];
            dstw[2048 + i] = srcR[i];
        }
    }

    const int wid  = tid >> 6;
    const int lane = tid & 63;
    const int g = lane >> 4;          // neighbor-slot group (Phase A)
    const int s = lane & 15;          // dim-chunk slot     (Phase A)
    const int row0 = blockIdx.x * 64;

    // -------- Phase A: this wave aggregates its own 16 rows into ldsa --------
    for (int i = 0; i < 16; ++i) {
        const int r = wid * 16 + i;   // local row; this wave reads it back in Phase B
        const int m = row0 + r;

        float a0 = 0.f, a1 = 0.f, a2 = 0.f, a3 = 0.f;
        float a4 = 0.f, a5 = 0.f, a6 = 0.f, a7 = 0.f;
        int cnt = 0;
        if (m < n) {
            cnt = deg[m];
            if (cnt > PAD) cnt = PAD;
            int beg = m * PAD;
            float b0 = 0.f, b1 = 0.f, b2 = 0.f, b3 = 0.f;
            float b4 = 0.f, b5 = 0.f, b6 = 0.f, b7 = 0.f;
            int j = 0;
            for (; j + 8 <= cnt; j += 8) {
                int nA = csr[beg + j + g];
                int nB = csr[beg + j + 4 + g];
                uint4 uA = *(const uint4*)(feat + (size_t)nA * D + s * 8);
                uint4 uB = *(const uint4*)(feat + (size_t)nB * D + s * 8);
                a0 += bf_lo(uA.x); a1 += bf_hi(uA.x);
                a2 += bf_lo(uA.y); a3 += bf_hi(uA.y);
                a4 += bf_lo(uA.z); a5 += bf_hi(uA.z);
                a6 += bf_lo(uA.w); a7 += bf_hi(uA.w);
                b0 += bf_lo(uB.x); b1 += bf_hi(uB.x);
                b2 += bf_lo(uB.y); b3 += bf_hi(uB.y);
                b4 += bf_lo(uB.z); b5 += bf_hi(uB.z);
                b6 += bf_lo(uB.w); b7 += bf_hi(uB.w);
            }
            if (j + 4 <= cnt) {
                int nA = csr[beg + j + g];
                uint4 uA = *(const uint4*)(feat + (size_t)nA * D + s * 8);
                a0 += bf_lo(uA.x); a1 += bf_hi(uA.x);
                a2 += bf_lo(uA.y); a3 += bf_hi(uA.y);
                a4 += bf_lo(uA.z); a5 += bf_hi(uA.z);
                a6 += bf_lo(uA.w); a7 += bf_hi(uA.w);
                j += 4;
            }
            int rem = cnt - j;               // 0..3
            if (g < rem) {
                int nA = csr[beg + j + g];
                uint4 uA = *(const uint4*)(feat + (size_t)nA * D + s * 8);
                b0 += bf_lo(uA.x); b1 += bf_hi(uA.x);
                b2 += bf_lo(uA.y); b3 += bf_hi(uA.y);
                b4 += bf_lo(uA.z); b5 += bf_hi(uA.z);
                b6 += bf_lo(uA.w); b7 += bf_hi(uA.w);
            }
            a0 += b0; a1 += b1; a2 += b2; a3 += b3;
            a4 += b4; a5 += b5; a6 += b6; a7 += b7;
        }

        // cross-group reduce (sum lanes {s, s+16, s+32, s+48})
        a0 += __shfl_xor(a0, 16, 64); a0 += __shfl_xor(a0, 32, 64);
        a1 += __shfl_xor(a1, 16, 64); a1 += __shfl_xor(a1, 32, 64);
        a2 += __shfl_xor(a2, 16, 64); a2 += __shfl_xor(a2, 32, 64);
        a3 += __shfl_xor(a3, 16, 64); a3 += __shfl_xor(a3, 32, 64);
        a4 += __shfl_xor(a4, 16, 64); a4 += __shfl_xor(a4, 32, 64);
        a5 += __shfl_xor(a5, 16, 64); a5 += __shfl_xor(a5, 32, 64);
        a6 += __shfl_xor(a6, 16, 64); a6 += __shfl_xor(a6, 32, 64);
        a7 += __shfl_xor(a7, 16, 64); a7 += __shfl_xor(a7, 32, 64);

        if (g == 0) {
            float sc = 1.0f / (float)(cnt > 0 ? cnt : 1);   // == R8 invd
            uint4 o;
            o.x = ((unsigned)f2bf(a1 * sc) << 16) | (unsigned)f2bf(a0 * sc);
            o.y = ((unsigned)f2bf(a3 * sc) << 16) | (unsigned)f2bf(a2 * sc);
            o.z = ((unsigned)f2bf(a5 * sc) << 16) | (unsigned)f2bf(a4 * sc);
            o.w = ((unsigned)f2bf(a7 * sc) << 16) | (unsigned)f2bf(a6 * sc);
            // chunk s of row r -> swizzled position s^(r&15): write banks 2-way (free)
            *(uint4*)&ldsa[r][(s ^ (r & 15)) * 8] = o;
        }
    }
    __syncthreads();   // weights (cross-wave); ldsa rows are wave-local

    // -------- Phase B: MFMA (R8-proven body; agg A-frags from ldsa) --------
    const int quad = lane >> 4;
    const int l16  = lane & 15;
    const int rloc = wid * 16 + l16;     // local row this lane covers
    int mc = row0 + rloc;
    if (mc >= n) mc = n - 1;             // clamp global reads; stores guarded

    bf16x8 af[2][4];
    const unsigned short* apX = feat + (size_t)mc * D + quad * 8;
#pragma unroll
    for (int kt = 0; kt < 4; ++kt) {
        int c = kt * 4 + quad;           // chunk index = (quad*8 + kt*32)/8
        af[0][kt] = *(const bf16x8*)&ldsa[rloc][(c ^ (rloc & 15)) * 8];
        af[1][kt] = *(const bf16x8*)(apX + kt * 32);
    }

    f32x4 acc[8];
#pragma unroll
    for (int c = 0; c < 8; ++c) acc[c] = (f32x4){0.f, 0.f, 0.f, 0.f};

#pragma unroll
    for (int half = 0; half < 2; ++half) {
#pragma unroll
        for (int kt = 0; kt < 4; ++kt) {
#pragma unroll
            for (int c = 0; c < 8; ++c) {
                bf16x8 bfrag = *(const bf16x8*)&ldsw[half][c * 4 + kt][lane * 8];
                acc[c] = __builtin_amdgcn_mfma_f32_16x16x32_bf16(af[half][kt], bfrag, acc[c], 0, 0, 0);
            }
        }
    }

#pragma unroll
    for (int c = 0; c < 8; ++c) {
        int col = c * 16 + l16;
        float bb = bias[col];
#pragma unroll
        for (int r = 0; r < 4; ++r) {
            int row = row0 + wid * 16 + quad * 4 + r;
            if (row < n) {
                float v = acc[c][r] + bb;
                if (mode) {
                    v = fmaxf(v, 0.0f);
                    out_bf[(size_t)row * D + col] = f2bf(v);
                } else {
                    out_f32[(size_t)row * D + col] = v;
                }
            }
        }
    }
}

// ---------------- launch ----------------

extern "C" void kernel_launch(void* const* d_in, const int* in_sizes, int n_in,
                              void* d_out, int out_size, void* d_ws, size_t ws_size,
                              hipStream_t stream) {
    const float* x   = (const float*)d_in[0];
    const int*   edg = (const int*)d_in[1];   // jnp.int64 downcast to int32 by JAX (x64 off)
    const float* wl1 = (const float*)d_in[2];
    const float* bl1 = (const float*)d_in[3];
    const float* wr1 = (const float*)d_in[4];
    const float* wl2 = (const float*)d_in[5];
    const float* bl2 = (const float*)d_in[6];
    const float* wr2 = (const float*)d_in[7];
    float* out = (float*)d_out;

    const int N = in_sizes[0] / D;
    const int E = in_sizes[1] / 2;
    const int* src = edg;
    const int* dst = edg + E;
    const int NB = (N + 255) / 256;           // 196 for N=50000

    char* ws = (char*)d_ws;
    size_t off = 0;
    auto carve = [&](size_t bytes) -> char* {
        char* p = ws + off;
        off = (off + bytes + 255) & ~(size_t)255;
        return p;
    };
    int*   cursor  = (int*)  carve((size_t)N * 4);            // degree after fill
    int*   csr     = (int*)  carve((size_t)N * PAD * 4);      // padded CSR, 12.8 MB
    unsigned short* xb   = (unsigned short*)carve((size_t)N * D * 2);
    unsigned short* hb   = (unsigned short*)carve((size_t)N * D * 2);
    unsigned short* wtl1 = (unsigned short*)carve(16384 * 2);
    unsigned short* wtr1 = (unsigned short*)carve(16384 * 2);
    unsigned short* wtl2 = (unsigned short*)carve(16384 * 2);
    unsigned short* wtr2 = (unsigned short*)carve(16384 * 2);
    (void)ws_size;   // ~39 MB

    int n4 = N * D / 4;
    int nb_f2bf = (n4 + 255) / 256;           // 6250
    int prep_blocks = nb_f2bf + 256 + NB;     // f2bf + wt + zero-cursor

    prep_kernel<<<prep_blocks, 256, 0, stream>>>(
        x, xb, n4, wl1, wr1, wl2, wr2, wtl1, wtr1, wtl2, wtr2, cursor, N, nb_f2bf);

    int eb = (E + 255) / 256;
    fill_pad_kernel<<<eb, 256, 0, stream>>>(src, dst, cursor, csr, E);

    int ntiles = (N + 63) / 64;               // 782 blocks, one 64-row tile each

    // Layer 1: hb = relu(agg(xb)@Wl1 + b1 + xb@Wr1)
    fused_agg_gemm_kernel<<<ntiles, 256, 0, stream>>>(
        xb, wtl1, wtr1, cursor, csr, bl1, hb, (float*)nullptr, N, 1);

    // Layer 2: out = agg(hb)@Wl2 + b2 + hb@Wr2
    fused_agg_gemm_kernel<<<ntiles, 256, 0, stream>>>(
        hb, wtl2, wtr2, cursor, csr, bl2, (unsigned short*)nullptr, out, N, 0);
}

// Round 10
// 208.623 us; speedup vs baseline: 1.4001x; 1.4001x over previous
//
#include <hip/hip_runtime.h>
#include <hip/hip_bf16.h>

// GraphSAGE 2-layer inference, N=50000, E=600000, D=128.
// R10: revert R9 fusion (occupancy-killed the gather). R8 6-launch pipeline +
//   - aggregate v3: 2 nodes per wave (2 lane-groups each), unroll-4 =>
//     4KB row data in flight per wave (2x R8) at unchanged occupancy;
//     unconditional clamped loads + 0/1-weight fmac masking (no exec thrash);
//     single shfl_xor(16) reduction.
//   - csr stored as ushort (src < 50000 < 65536): fill write-back and agg
//     index traffic halved; csr = 6.4MB (L2-resident).
//   - fill_pad reads edges as int2 (2 edges/thread).

#define D 128
#define PAD 64

typedef __attribute__((ext_vector_type(8))) short bf16x8;
typedef __attribute__((ext_vector_type(4))) float f32x4;

__device__ __forceinline__ unsigned short f2bf(float f) {
    __hip_bfloat16 b = __float2bfloat16(f);
    return *(unsigned short*)&b;
}
__device__ __forceinline__ float bf_lo(unsigned u) { return __uint_as_float(u << 16); }
__device__ __forceinline__ float bf_hi(unsigned u) { return __uint_as_float(u & 0xffff0000u); }

// ---------------- fused prep: zero cursor + f2bf(x) + wt fragment transpose (R8-proven) ----------------
__global__ __launch_bounds__(256) void prep_kernel(
    const float* __restrict__ x, unsigned short* __restrict__ xb, int n4,
    const float* __restrict__ w0, const float* __restrict__ w1,
    const float* __restrict__ w2, const float* __restrict__ w3,
    unsigned short* __restrict__ o0, unsigned short* __restrict__ o1,
    unsigned short* __restrict__ o2, unsigned short* __restrict__ o3,
    int* __restrict__ cursor, int n, int nb_f2bf) {
    int b = blockIdx.x;
    int tid = threadIdx.x;
    if (b < nb_f2bf) {
        int i = b * 256 + tid;
        if (i < n4) {
            float4 v = ((const float4*)x)[i];
            ushort4 o;
            o.x = f2bf(v.x); o.y = f2bf(v.y); o.z = f2bf(v.z); o.w = f2bf(v.w);
            ((ushort4*)xb)[i] = o;
        }
    } else if (b < nb_f2bf + 256) {
        // weights fp32 [k][n] -> bf16 MFMA-fragment order (R6..R8-proven):
        // frag f = c*4+kt; elem [f*512 + lane*8 + j] = W[kt*32+(lane>>4)*8+j][c*16+(lane&15)]
        int t = (b - nb_f2bf) * 256 + tid;       // 0 .. 65535
        int m = t >> 14;
        int r = t & 16383;
        int f = r >> 9;
        int q = r & 511;
        int lane = q >> 3, j = q & 7;
        int kt = f & 3, c = f >> 2;
        int k  = kt * 32 + (lane >> 4) * 8 + j;
        int nn = c * 16 + (lane & 15);
        const float* w = (m == 0) ? w0 : (m == 1) ? w1 : (m == 2) ? w2 : w3;
        unsigned short* o = (m == 0) ? o0 : (m == 1) ? o1 : (m == 2) ? o2 : o3;
        o[r] = f2bf(w[k * 128 + nn]);
    } else {
        int i = (b - nb_f2bf - 256) * 256 + tid;
        if (i < n) cursor[i] = 0;
    }
}

// ---------------- padded-CSR fill: ushort slots, 2 edges/thread ----------------
__global__ void fill_pad_kernel(const int* __restrict__ src, const int* __restrict__ dst,
                                int* __restrict__ cursor, unsigned short* __restrict__ csr,
                                int E) {
    int i = blockIdx.x * blockDim.x + threadIdx.x;   // edge-pair index
    int e0 = i * 2;
    if (e0 < E) {
        int2 s2 = ((const int2*)src)[i];
        int2 d2 = ((const int2*)dst)[i];
        int p = atomicAdd(&cursor[d2.x], 1);
        if (p < PAD) csr[d2.x * PAD + p] = (unsigned short)s2.x;
        if (e0 + 1 < E) {
            p = atomicAdd(&cursor[d2.y], 1);
            if (p < PAD) csr[d2.y * PAD + p] = (unsigned short)s2.y;
        }
    }
}

// ---------------- aggregation v3: 2 nodes per wave, 4KB in flight ----------------
// lane = g*16 + s; g in {0,1} -> node m0, g in {2,3} -> node m1; gg = g&1 is the
// neighbor-slot parity. One load instruction covers 4 rows (2 per node); the
// k-unroll issues 4 such loads (16 rows) before any accumulate. Invalid slots
// clamp to slot 0 (poison 0xAAAA -> idx 43690 < N, safe) and contribute with
// weight 0 via fmac. Reduce = one shfl_xor(16); groups 0/2 store the two rows.
__global__ __launch_bounds__(256) void aggregate_bf16_kernel(
    const unsigned short* __restrict__ feat, const int* __restrict__ deg,
    const unsigned short* __restrict__ csr, unsigned short* __restrict__ agg, int n) {
    int pair = (blockIdx.x * 256 + threadIdx.x) >> 6;
    int lane = threadIdx.x & 63;
    int m0 = pair * 2;
    if (m0 >= n) return;
    int m1 = m0 + 1;
    const int g  = lane >> 4;
    const int s  = lane & 15;
    const int gg = g & 1;

    int cnt0 = deg[m0]; if (cnt0 > PAD) cnt0 = PAD;
    int cnt1 = (m1 < n) ? deg[m1] : 0; if (cnt1 > PAD) cnt1 = PAD;
    const int mycnt = (g < 2) ? cnt0 : cnt1;
    const int mybeg = ((g < 2) ? m0 : m1) * PAD;
    int cmax = cnt0 > cnt1 ? cnt0 : cnt1;

    float a0 = 0.f, a1 = 0.f, a2 = 0.f, a3 = 0.f;
    float a4 = 0.f, a5 = 0.f, a6 = 0.f, a7 = 0.f;

    for (int j = 0; j < cmax; j += 8) {
        uint4 u[4];
        float w[4];
#pragma unroll
        for (int k = 0; k < 4; ++k) {
            int p = j + 2 * k + gg;
            w[k] = (p < mycnt) ? 1.0f : 0.0f;
            int pc = (p < mycnt) ? p : 0;
            int idx = csr[mybeg + pc];
            u[k] = *(const uint4*)(feat + (size_t)idx * D + s * 8);
        }
#pragma unroll
        for (int k = 0; k < 4; ++k) {
            a0 += w[k] * bf_lo(u[k].x); a1 += w[k] * bf_hi(u[k].x);
            a2 += w[k] * bf_lo(u[k].y); a3 += w[k] * bf_hi(u[k].y);
            a4 += w[k] * bf_lo(u[k].z); a5 += w[k] * bf_hi(u[k].z);
            a6 += w[k] * bf_lo(u[k].w); a7 += w[k] * bf_hi(u[k].w);
        }
    }

    // combine the two slot-parity groups of each node: lanes l and l^16
    a0 += __shfl_xor(a0, 16, 64);
    a1 += __shfl_xor(a1, 16, 64);
    a2 += __shfl_xor(a2, 16, 64);
    a3 += __shfl_xor(a3, 16, 64);
    a4 += __shfl_xor(a4, 16, 64);
    a5 += __shfl_xor(a5, 16, 64);
    a6 += __shfl_xor(a6, 16, 64);
    a7 += __shfl_xor(a7, 16, 64);

    if (gg == 0) {                       // g==0 -> node m0, g==2 -> node m1
        int mym = (g < 2) ? m0 : m1;
        if (mym < n) {
            int c = mycnt;
            float sc = 1.0f / (float)(c > 0 ? c : 1);
            uint4 o;
            o.x = ((unsigned)f2bf(a1 * sc) << 16) | (unsigned)f2bf(a0 * sc);
            o.y = ((unsigned)f2bf(a3 * sc) << 16) | (unsigned)f2bf(a2 * sc);
            o.z = ((unsigned)f2bf(a5 * sc) << 16) | (unsigned)f2bf(a4 * sc);
            o.w = ((unsigned)f2bf(a7 * sc) << 16) | (unsigned)f2bf(a6 * sc);
            *(uint4*)(agg + (size_t)mym * D + s * 8) = o;
        }
    }
}

// ---------------- MFMA GEMM with LDS-staged fragment-ordered weights (R8-proven) ----------------
__global__ __launch_bounds__(256) void gemm_mfma_kernel(
    const unsigned short* __restrict__ A, const unsigned short* __restrict__ X,
    const unsigned short* __restrict__ WfL, const unsigned short* __restrict__ WfR,
    const float* __restrict__ bias, unsigned short* __restrict__ out_bf,
    float* __restrict__ out_f32, int n, int mode, int ntiles) {
    __shared__ unsigned short lds[2][32][512];   // 64 KB

    const int tid = threadIdx.x;
    {
        const uint4* srcL = (const uint4*)WfL;   // 2048 uint4
        const uint4* srcR = (const uint4*)WfR;
        uint4* dst = (uint4*)&lds[0][0][0];
#pragma unroll
        for (int it = 0; it < 8; ++it) {
            int i = it * 256 + tid;
            dst[i]        = srcL[i];
            dst[2048 + i] = srcR[i];
        }
    }
    __syncthreads();

    const int wid = tid >> 6;
    const int lane = tid & 63;
    const int quad = lane >> 4;
    const int l16 = lane & 15;

    for (int tile = blockIdx.x; tile < ntiles; tile += gridDim.x) {
        const int row0 = tile * 64 + wid * 16;
        int m = row0 + l16;
        if (m >= n) m = n - 1;   // clamp reads; stores guarded

        bf16x8 af[2][4];
        const unsigned short* apA = A + (size_t)m * D + quad * 8;
        const unsigned short* apX = X + (size_t)m * D + quad * 8;
#pragma unroll
        for (int kt = 0; kt < 4; ++kt) {
            af[0][kt] = *(const bf16x8*)(apA + kt * 32);
            af[1][kt] = *(const bf16x8*)(apX + kt * 32);
        }

        f32x4 acc[8];
#pragma unroll
        for (int c = 0; c < 8; ++c) acc[c] = (f32x4){0.f, 0.f, 0.f, 0.f};

#pragma unroll
        for (int half = 0; half < 2; ++half) {
#pragma unroll
            for (int kt = 0; kt < 4; ++kt) {
#pragma unroll
                for (int c = 0; c < 8; ++c) {
                    bf16x8 bfrag = *(const bf16x8*)&lds[half][c * 4 + kt][lane * 8];
                    acc[c] = __builtin_amdgcn_mfma_f32_16x16x32_bf16(af[half][kt], bfrag, acc[c], 0, 0, 0);
                }
            }
        }

#pragma unroll
        for (int c = 0; c < 8; ++c) {
            int col = c * 16 + l16;
            float bb = bias[col];
#pragma unroll
            for (int r = 0; r < 4; ++r) {
                int row = row0 + quad * 4 + r;
                if (row < n) {
                    float v = acc[c][r] + bb;
                    if (mode) {
                        v = fmaxf(v, 0.0f);
                        out_bf[(size_t)row * D + col] = f2bf(v);
                    } else {
                        out_f32[(size_t)row * D + col] = v;
                    }
                }
            }
        }
    }
}

// ---------------- launch ----------------

extern "C" void kernel_launch(void* const* d_in, const int* in_sizes, int n_in,
                              void* d_out, int out_size, void* d_ws, size_t ws_size,
                              hipStream_t stream) {
    const float* x   = (const float*)d_in[0];
    const int*   edg = (const int*)d_in[1];   // jnp.int64 downcast to int32 by JAX (x64 off)
    const float* wl1 = (const float*)d_in[2];
    const float* bl1 = (const float*)d_in[3];
    const float* wr1 = (const float*)d_in[4];
    const float* wl2 = (const float*)d_in[5];
    const float* bl2 = (const float*)d_in[6];
    const float* wr2 = (const float*)d_in[7];
    float* out = (float*)d_out;

    const int N = in_sizes[0] / D;
    const int E = in_sizes[1] / 2;
    const int* src = edg;
    const int* dst = edg + E;
    const int NB = (N + 255) / 256;           // 196 for N=50000

    char* ws = (char*)d_ws;
    size_t off = 0;
    auto carve = [&](size_t bytes) -> char* {
        char* p = ws + off;
        off = (off + bytes + 255) & ~(size_t)255;
        return p;
    };
    int*   cursor  = (int*)  carve((size_t)N * 4);                 // degree after fill
    unsigned short* csr = (unsigned short*)carve((size_t)N * PAD * 2);  // 6.4 MB
    unsigned short* xb   = (unsigned short*)carve((size_t)N * D * 2);
    unsigned short* hb   = (unsigned short*)carve((size_t)N * D * 2);
    unsigned short* aggb = (unsigned short*)carve((size_t)N * D * 2);
    unsigned short* wtl1 = (unsigned short*)carve(16384 * 2);
    unsigned short* wtr1 = (unsigned short*)carve(16384 * 2);
    unsigned short* wtl2 = (unsigned short*)carve(16384 * 2);
    unsigned short* wtr2 = (unsigned short*)carve(16384 * 2);
    (void)ws_size;   // ~45 MB (R4's 54.6 MB proven fine)

    int n4 = N * D / 4;
    int nb_f2bf = (n4 + 255) / 256;           // 6250
    int prep_blocks = nb_f2bf + 256 + NB;     // f2bf + wt + zero-cursor

    prep_kernel<<<prep_blocks, 256, 0, stream>>>(
        x, xb, n4, wl1, wr1, wl2, wr2, wtl1, wtr1, wtl2, wtr2, cursor, N, nb_f2bf);

    int epairs = (E + 1) / 2;
    int eb = (epairs + 255) / 256;
    fill_pad_kernel<<<eb, 256, 0, stream>>>(src, dst, cursor, csr, E);

    int pairs = (N + 1) / 2;                  // 25000
    int agg_blocks = (pairs + 3) / 4;         // 4 waves (pairs) per block
    int ntiles = (N + 63) / 64;               // 782
    int gemm_blocks = (ntiles + 1) / 2;       // 391: 2 tiles per block

    // Layer 1
    aggregate_bf16_kernel<<<agg_blocks, 256, 0, stream>>>(xb, cursor, csr, aggb, N);
    gemm_mfma_kernel<<<gemm_blocks, 256, 0, stream>>>(aggb, xb, wtl1, wtr1, bl1, hb, (float*)nullptr, N, 1, ntiles);

    // Layer 2
    aggregate_bf16_kernel<<<agg_blocks, 256, 0, stream>>>(hb, cursor, csr, aggb, N);
    gemm_mfma_kernel<<<gemm_blocks, 256, 0, stream>>>(aggb, hb, wtl2, wtr2, bl2, (unsigned short*)nullptr, out, N, 0, ntiles);
}

// Round 11
// 201.017 us; speedup vs baseline: 1.4531x; 1.0378x over previous
//
#include <hip/hip_runtime.h>
#include <hip/hip_bf16.h>

// GraphSAGE 2-layer inference, N=50000, E=600000, D=128.
// R11: fusion retry with the R9 occupancy bug fixed.
//   prep:     zero cursor + f2bf(x) + weight fragment-transpose   (R8/R10-proven)
//   fill_pad: padded ushort CSR                                    (R10-proven)
//   fused1:   hb  = relu(mean-agg(xb)@Wl1 + b1 + xb@Wr1)
//   fused2:   out =      mean-agg(hb)@Wl2 + b2 + hb@Wr2
// Fused kernel: LDS = 16KB agg tile ONLY (R9's 64KB weight stage was the
// occupancy killer: 2 blocks/CU). B-fragments are read straight from global
// in MFMA fragment order -> wave-uniform base + lane*16B = coalesced 1KB
// reads of a 32KB L2-hot table. __launch_bounds__(256,4) caps VGPR<=128 ->
// 16 waves/CU; R10 showed agg is fabric-BW-bound at this occupancy level.
// Phase A = R10-v3 gather (2 nodes/wave, 4KB in flight) writing the XOR-
// swizzled LDS tile (R9-proven layout); Phase B = R8-proven MFMA body.

#define D 128
#define PAD 64

typedef __attribute__((ext_vector_type(8))) short bf16x8;
typedef __attribute__((ext_vector_type(4))) float f32x4;

__device__ __forceinline__ unsigned short f2bf(float f) {
    __hip_bfloat16 b = __float2bfloat16(f);
    return *(unsigned short*)&b;
}
__device__ __forceinline__ float bf_lo(unsigned u) { return __uint_as_float(u << 16); }
__device__ __forceinline__ float bf_hi(unsigned u) { return __uint_as_float(u & 0xffff0000u); }

// ---------------- fused prep: zero cursor + f2bf(x) + wt fragment transpose (R8-proven) ----------------
__global__ __launch_bounds__(256) void prep_kernel(
    const float* __restrict__ x, unsigned short* __restrict__ xb, int n4,
    const float* __restrict__ w0, const float* __restrict__ w1,
    const float* __restrict__ w2, const float* __restrict__ w3,
    unsigned short* __restrict__ o0, unsigned short* __restrict__ o1,
    unsigned short* __restrict__ o2, unsigned short* __restrict__ o3,
    int* __restrict__ cursor, int n, int nb_f2bf) {
    int b = blockIdx.x;
    int tid = threadIdx.x;
    if (b < nb_f2bf) {
        int i = b * 256 + tid;
        if (i < n4) {
            float4 v = ((const float4*)x)[i];
            ushort4 o;
            o.x = f2bf(v.x); o.y = f2bf(v.y); o.z = f2bf(v.z); o.w = f2bf(v.w);
            ((ushort4*)xb)[i] = o;
        }
    } else if (b < nb_f2bf + 256) {
        // weights fp32 [k][n] -> bf16 MFMA-fragment order (R6..R10-proven):
        // frag f = c*4+kt; elem [f*512 + lane*8 + j] = W[kt*32+(lane>>4)*8+j][c*16+(lane&15)]
        int t = (b - nb_f2bf) * 256 + tid;       // 0 .. 65535
        int m = t >> 14;
        int r = t & 16383;
        int f = r >> 9;
        int q = r & 511;
        int lane = q >> 3, j = q & 7;
        int kt = f & 3, c = f >> 2;
        int k  = kt * 32 + (lane >> 4) * 8 + j;
        int nn = c * 16 + (lane & 15);
        const float* w = (m == 0) ? w0 : (m == 1) ? w1 : (m == 2) ? w2 : w3;
        unsigned short* o = (m == 0) ? o0 : (m == 1) ? o1 : (m == 2) ? o2 : o3;
        o[r] = f2bf(w[k * 128 + nn]);
    } else {
        int i = (b - nb_f2bf - 256) * 256 + tid;
        if (i < n) cursor[i] = 0;
    }
}

// ---------------- padded-CSR fill: ushort slots, 2 edges/thread (R10-proven) ----------------
__global__ void fill_pad_kernel(const int* __restrict__ src, const int* __restrict__ dst,
                                int* __restrict__ cursor, unsigned short* __restrict__ csr,
                                int E) {
    int i = blockIdx.x * blockDim.x + threadIdx.x;   // edge-pair index
    int e0 = i * 2;
    if (e0 < E) {
        int2 s2 = ((const int2*)src)[i];
        int2 d2 = ((const int2*)dst)[i];
        int p = atomicAdd(&cursor[d2.x], 1);
        if (p < PAD) csr[d2.x * PAD + p] = (unsigned short)s2.x;
        if (e0 + 1 < E) {
            p = atomicAdd(&cursor[d2.y], 1);
            if (p < PAD) csr[d2.y * PAD + p] = (unsigned short)s2.y;
        }
    }
}

// ---------------- fused aggregate + MFMA GEMM (16KB LDS, global frag-ordered B) ----------------
// out = mean-agg(feat)@Wl + feat@Wr + bias (optional relu).
__global__ __launch_bounds__(256, 4) void fused_agg_gemm_kernel(
    const unsigned short* __restrict__ feat,
    const unsigned short* __restrict__ WfL, const unsigned short* __restrict__ WfR,
    const int* __restrict__ deg, const unsigned short* __restrict__ csr,
    const float* __restrict__ bias, unsigned short* __restrict__ out_bf,
    float* __restrict__ out_f32, int n, int mode) {
    __shared__ unsigned short ldsa[64][128];      // 16 KB agg tile, XOR-swizzled chunks

    const int tid  = threadIdx.x;
    const int wid  = tid >> 6;
    const int lane = tid & 63;
    const int row0 = blockIdx.x * 64;

    // -------- Phase A: R10-v3 gather, 2 nodes per pass, 8 passes = 16 rows/wave --------
    {
        const int g  = lane >> 4;
        const int s  = lane & 15;
        const int gg = g & 1;          // neighbor-slot parity
        const int nsel = g >> 1;       // 0 -> even row, 1 -> odd row

        for (int ii = 0; ii < 8; ++ii) {
            int r0 = wid * 16 + ii * 2;
            int m0 = row0 + r0;
            int m1 = m0 + 1;
            int cnt0 = (m0 < n) ? deg[m0] : 0; if (cnt0 > PAD) cnt0 = PAD;
            int cnt1 = (m1 < n) ? deg[m1] : 0; if (cnt1 > PAD) cnt1 = PAD;
            int mym   = nsel ? m1 : m0;
            int mycnt = nsel ? cnt1 : cnt0;
            int mybeg = (mym < n ? mym : 0) * PAD;
            int cmax  = cnt0 > cnt1 ? cnt0 : cnt1;

            float a0 = 0.f, a1 = 0.f, a2 = 0.f, a3 = 0.f;
            float a4 = 0.f, a5 = 0.f, a6 = 0.f, a7 = 0.f;

            for (int j = 0; j < cmax; j += 8) {
                uint4 u[4];
                float w[4];
#pragma unroll
                for (int k = 0; k < 4; ++k) {
                    int p = j + 2 * k + gg;
                    w[k] = (p < mycnt) ? 1.0f : 0.0f;
                    int pc = (p < mycnt) ? p : 0;
                    int idx = csr[mybeg + pc];   // unwritten slot0 = poison 43690 < N: safe, weight 0
                    u[k] = *(const uint4*)(feat + (size_t)idx * D + s * 8);
                }
#pragma unroll
                for (int k = 0; k < 4; ++k) {
                    a0 += w[k] * bf_lo(u[k].x); a1 += w[k] * bf_hi(u[k].x);
                    a2 += w[k] * bf_lo(u[k].y); a3 += w[k] * bf_hi(u[k].y);
                    a4 += w[k] * bf_lo(u[k].z); a5 += w[k] * bf_hi(u[k].z);
                    a6 += w[k] * bf_lo(u[k].w); a7 += w[k] * bf_hi(u[k].w);
                }
            }

            // combine slot parities: lanes l and l^16
            a0 += __shfl_xor(a0, 16, 64);
            a1 += __shfl_xor(a1, 16, 64);
            a2 += __shfl_xor(a2, 16, 64);
            a3 += __shfl_xor(a3, 16, 64);
            a4 += __shfl_xor(a4, 16, 64);
            a5 += __shfl_xor(a5, 16, 64);
            a6 += __shfl_xor(a6, 16, 64);
            a7 += __shfl_xor(a7, 16, 64);

            if (gg == 0) {               // g==0 writes row r0, g==2 writes row r0+1
                int r = r0 + nsel;
                float sc = 1.0f / (float)(mycnt > 0 ? mycnt : 1);
                uint4 o;
                o.x = ((unsigned)f2bf(a1 * sc) << 16) | (unsigned)f2bf(a0 * sc);
                o.y = ((unsigned)f2bf(a3 * sc) << 16) | (unsigned)f2bf(a2 * sc);
                o.z = ((unsigned)f2bf(a5 * sc) << 16) | (unsigned)f2bf(a4 * sc);
                o.w = ((unsigned)f2bf(a7 * sc) << 16) | (unsigned)f2bf(a6 * sc);
                // chunk s of row r -> swizzled pos s^(r&15) (R9-proven layout)
                *(uint4*)&ldsa[r][(s ^ (r & 15)) * 8] = o;
            }
        }
    }
    __syncthreads();   // cheap; guarantees LDS visibility before Phase B reads

    // -------- Phase B: MFMA (R8-proven body; B-frags from GLOBAL frag-ordered) --------
    const int quad = lane >> 4;
    const int l16  = lane & 15;
    const int rloc = wid * 16 + l16;
    int mc = row0 + rloc;
    if (mc >= n) mc = n - 1;             // clamp global reads; stores guarded

    bf16x8 af[2][4];
    const unsigned short* apX = feat + (size_t)mc * D + quad * 8;
#pragma unroll
    for (int kt = 0; kt < 4; ++kt) {
        int c = kt * 4 + quad;           // chunk index = (quad*8 + kt*32)/8
        af[0][kt] = *(const bf16x8*)&ldsa[rloc][(c ^ (rloc & 15)) * 8];
        af[1][kt] = *(const bf16x8*)(apX + kt * 32);
    }

    f32x4 acc[8];
#pragma unroll
    for (int c = 0; c < 8; ++c) acc[c] = (f32x4){0.f, 0.f, 0.f, 0.f};

#pragma unroll
    for (int half = 0; half < 2; ++half) {
        const unsigned short* wp = half ? WfR : WfL;
#pragma unroll
        for (int kt = 0; kt < 4; ++kt) {
#pragma unroll
            for (int c = 0; c < 8; ++c) {
                // fragment f = c*4+kt; wave-uniform base + lane*16B: coalesced 1KB
                bf16x8 bfrag = *(const bf16x8*)(wp + (size_t)(c * 4 + kt) * 512 + lane * 8);
                acc[c] = __builtin_amdgcn_mfma_f32_16x16x32_bf16(af[half][kt], bfrag, acc[c], 0, 0, 0);
            }
        }
    }

#pragma unroll
    for (int c = 0; c < 8; ++c) {
        int col = c * 16 + l16;
        float bb = bias[col];
#pragma unroll
        for (int r = 0; r < 4; ++r) {
            int row = row0 + wid * 16 + quad * 4 + r;
            if (row < n) {
                float v = acc[c][r] + bb;
                if (mode) {
                    v = fmaxf(v, 0.0f);
                    out_bf[(size_t)row * D + col] = f2bf(v);
                } else {
                    out_f32[(size_t)row * D + col] = v;
                }
            }
        }
    }
}

// ---------------- launch ----------------

extern "C" void kernel_launch(void* const* d_in, const int* in_sizes, int n_in,
                              void* d_out, int out_size, void* d_ws, size_t ws_size,
                              hipStream_t stream) {
    const float* x   = (const float*)d_in[0];
    const int*   edg = (const int*)d_in[1];   // jnp.int64 downcast to int32 by JAX (x64 off)
    const float* wl1 = (const float*)d_in[2];
    const float* bl1 = (const float*)d_in[3];
    const float* wr1 = (const float*)d_in[4];
    const float* wl2 = (const float*)d_in[5];
    const float* bl2 = (const float*)d_in[6];
    const float* wr2 = (const float*)d_in[7];
    float* out = (float*)d_out;

    const int N = in_sizes[0] / D;
    const int E = in_sizes[1] / 2;
    const int* src = edg;
    const int* dst = edg + E;
    const int NB = (N + 255) / 256;           // 196 for N=50000

    char* ws = (char*)d_ws;
    size_t off = 0;
    auto carve = [&](size_t bytes) -> char* {
        char* p = ws + off;
        off = (off + bytes + 255) & ~(size_t)255;
        return p;
    };
    int*   cursor  = (int*)  carve((size_t)N * 4);                      // degree after fill
    unsigned short* csr = (unsigned short*)carve((size_t)N * PAD * 2);  // 6.4 MB
    unsigned short* xb   = (unsigned short*)carve((size_t)N * D * 2);
    unsigned short* hb   = (unsigned short*)carve((size_t)N * D * 2);
    unsigned short* wtl1 = (unsigned short*)carve(16384 * 2);
    unsigned short* wtr1 = (unsigned short*)carve(16384 * 2);
    unsigned short* wtl2 = (unsigned short*)carve(16384 * 2);
    unsigned short* wtr2 = (unsigned short*)carve(16384 * 2);
    (void)ws_size;   // ~32 MB

    int n4 = N * D / 4;
    int nb_f2bf = (n4 + 255) / 256;           // 6250
    int prep_blocks = nb_f2bf + 256 + NB;     // f2bf + wt + zero-cursor

    prep_kernel<<<prep_blocks, 256, 0, stream>>>(
        x, xb, n4, wl1, wr1, wl2, wr2, wtl1, wtr1, wtl2, wtr2, cursor, N, nb_f2bf);

    int epairs = (E + 1) / 2;
    int eb = (epairs + 255) / 256;
    fill_pad_kernel<<<eb, 256, 0, stream>>>(src, dst, cursor, csr, E);

    int ntiles = (N + 63) / 64;               // 782 blocks, one 64-row tile each

    // Layer 1: hb = relu(agg(xb)@Wl1 + b1 + xb@Wr1)
    fused_agg_gemm_kernel<<<ntiles, 256, 0, stream>>>(
        xb, wtl1, wtr1, cursor, csr, bl1, hb, (float*)nullptr, N, 1);

    // Layer 2: out = agg(hb)@Wl2 + b2 + hb@Wr2
    fused_agg_gemm_kernel<<<ntiles, 256, 0, stream>>>(
        hb, wtl2, wtr2, cursor, csr, bl2, (unsigned short*)nullptr, out, N, 0);
}